// Round 5
// baseline (122.646 us; speedup 1.0000x reference)
//
#include <hip/hip_runtime.h>

// SOM/PSO hybrid update, MI355X — 2 kernels + 1 memset.
// memset: d_ws[0] <- 0xFF..FF (atomicMin identity).
// Pass 1: argmin of squared distance; per-block min -> ONE device-scope
//         atomicMin(u64) on the encoded (distbits<<32)|idx result.
// Pass 2: masked PSO update, DESCENDING row order (LRU-friendly vs pass 1).
//         ALL loads normal (nt loads proven -15us poison in R2/R4);
//         outputs use NONTEMPORAL STORES (proven good in R3: don't evict
//         particles from L3).

typedef float v4f __attribute__((ext_vector_type(4)));

constexpr int DIM     = 512;
constexpr int NPART   = 256 * 256;
constexpr int THREADS = 256;
constexpr int WPB     = THREADS / 64;        // 4 waves per block
constexpr int DIST_BLOCKS = 2048;            // 8192 waves -> 8 rows/wave
constexpr int DIST_WAVES  = DIST_BLOCKS * WPB;
constexpr int DIST_RPW    = NPART / DIST_WAVES;   // 8

__global__ __launch_bounds__(THREADS)
void som_dist(const float* __restrict__ input,
              const float* __restrict__ particles,
              unsigned long long* __restrict__ result) {
    const int lane = threadIdx.x & 63;
    const int wave = threadIdx.x >> 6;
    const int gwave = blockIdx.x * WPB + wave;

    const v4f* in4 = (const v4f*)input;
    const v4f i0 = in4[lane];          // floats [lane*4 .. lane*4+3]
    const v4f i1 = in4[64 + lane];     // floats [256 + lane*4 ..]

    unsigned long long best = ~0ull;
    #pragma unroll
    for (int i = 0; i < DIST_RPW; i += 2) {
        const int rowA = gwave + i * DIST_WAVES;
        const int rowB = rowA + DIST_WAVES;
        const v4f* pa = (const v4f*)(particles + (size_t)rowA * DIM);
        const v4f* pb = (const v4f*)(particles + (size_t)rowB * DIM);
        v4f a0 = pa[lane], a1 = pa[64 + lane];
        v4f b0 = pb[lane], b1 = pb[64 + lane];

        v4f t, accA, accB;
        t = i0 - a0; accA  = t * t;
        t = i1 - a1; accA += t * t;
        t = i0 - b0; accB  = t * t;
        t = i1 - b1; accB += t * t;
        float dA = accA.x + accA.y + accA.z + accA.w;
        float dB = accB.x + accB.y + accB.z + accB.w;
        #pragma unroll
        for (int off = 32; off >= 1; off >>= 1) {
            dA += __shfl_xor(dA, off, 64);
            dB += __shfl_xor(dB, off, 64);
        }
        unsigned long long encA =
            ((unsigned long long)__float_as_uint(dA) << 32) | (unsigned int)rowA;
        unsigned long long encB =
            ((unsigned long long)__float_as_uint(dB) << 32) | (unsigned int)rowB;
        best = (encA < best) ? encA : best;
        best = (encB < best) ? encB : best;
    }

    __shared__ unsigned long long smin[WPB];
    if (lane == 0) smin[wave] = best;
    __syncthreads();
    if (threadIdx.x == 0) {
        unsigned long long b = smin[0];
        #pragma unroll
        for (int i = 1; i < WPB; ++i) b = (smin[i] < b) ? smin[i] : b;
        atomicMin(result, b);   // device-scope, 2048 ops on one address
    }
}

__global__ __launch_bounds__(THREADS)
void som_update(const float* __restrict__ particles,
                const float* __restrict__ velocities,
                const float* __restrict__ r1,
                const float* __restrict__ r2,
                const int*   __restrict__ grid_loc,
                const int*   __restrict__ iter_num,
                const unsigned long long* __restrict__ bmu_enc,
                float* __restrict__ out_p,
                float* __restrict__ out_v) {
    const int lane = threadIdx.x & 63;
    const int wave = threadIdx.x >> 6;
    // descending: rows touched last by som_dist are read first here (L3 LRU)
    const int row  = (NPART - 1) - (blockIdx.x * WPB + wave);

    const int bmu = (int)(unsigned int)(bmu_enc[0] & 0xffffffffull);
    const float decay   = 1.0f - (float)iter_num[0] * (1.0f / 100.0f);
    const float radius  = 0.3f * decay;
    const float sigma_d = 128.0f * decay;

    const int2 gl = ((const int2*)grid_loc)[row];
    const int2 bl = ((const int2*)grid_loc)[bmu];
    const float dx = (float)gl.x - (float)bl.x;
    const float dy = (float)gl.y - (float)bl.y;
    const float d2 = dx * dx + dy * dy;
    const float nb = expf(-d2 / (sigma_d * sigma_d));
    const bool upd = (1.0f - nb) <= radius;   // global_nbest == exp(0) == 1 exactly

    const size_t base = (size_t)row * DIM;
    const v4f* p4  = (const v4f*)(particles  + base);
    const v4f* vv4 = (const v4f*)(velocities + base);
    v4f* op4 = (v4f*)(out_p + base);
    v4f* ov4 = (v4f*)(out_v + base);

    if (!upd) {
        // wave-uniform branch: plain copy, skip r1/r2 reads
        v4f a0 = p4[lane], a1 = p4[64 + lane];
        v4f c0 = vv4[lane], c1 = vv4[64 + lane];
        __builtin_nontemporal_store(a0, op4 + lane);
        __builtin_nontemporal_store(a1, op4 + 64 + lane);
        __builtin_nontemporal_store(c0, ov4 + lane);
        __builtin_nontemporal_store(c1, ov4 + 64 + lane);
    } else {
        const v4f* g4 = (const v4f*)(particles + (size_t)bmu * DIM);
        const v4f* x4 = (const v4f*)(r1 + base);
        const v4f* y4 = (const v4f*)(r2 + base);
        #pragma unroll
        for (int h = 0; h < 2; ++h) {
            const int idx = h * 64 + lane;
            v4f p = p4[idx];
            v4f v = vv4[idx];
            v4f a = x4[idx];
            v4f c = y4[idx];
            v4f df = g4[idx] - p;
            v4f vn = 0.5f * v + 0.1f * a * df + 0.1f * c * df;
            v4f po = p + vn;
            __builtin_nontemporal_store(vn, ov4 + idx);
            __builtin_nontemporal_store(po, op4 + idx);
        }
    }
}

extern "C" void kernel_launch(void* const* d_in, const int* in_sizes, int n_in,
                              void* d_out, int out_size, void* d_ws, size_t ws_size,
                              hipStream_t stream) {
    const float* input      = (const float*)d_in[0];
    const float* particles  = (const float*)d_in[1];
    const float* velocities = (const float*)d_in[2];
    const float* r1         = (const float*)d_in[3];
    const float* r2         = (const float*)d_in[4];
    const int*   grid_loc   = (const int*)d_in[5];
    const int*   iter_num   = (const int*)d_in[6];

    float* out_p = (float*)d_out;
    float* out_v = out_p + (size_t)NPART * DIM;

    unsigned long long* final_enc = (unsigned long long*)d_ws;

    hipMemsetAsync(final_enc, 0xFF, sizeof(unsigned long long), stream);
    som_dist<<<DIST_BLOCKS, THREADS, 0, stream>>>(input, particles, final_enc);
    som_update<<<NPART / WPB, THREADS, 0, stream>>>(
        particles, velocities, r1, r2, grid_loc, iter_num, final_enc,
        out_p, out_v);
}

// Round 6
// 117.551 us; speedup vs baseline: 1.0433x; 1.0433x over previous
//
#include <hip/hip_runtime.h>

// SOM/PSO hybrid update, MI355X — 3-kernel pipeline + speculative copy.
// Pass 1 (som_dist): read particle rows (in registers anyway), write
//         out_p = particles for ALL rows (nt store), compute distances,
//         per-block argmin partial. No memset node (R4/R5: graph fill node
//         costs ~11 us in serialization).
// Pass 2 (som_reduce): 1-block min-reduce of 2048 partials -> encoded
//         (distbits<<32)|idx.
// Pass 3 (som_update): DESCENDING rows. Unmasked rows (~80%): out_v = v only
//         (p never re-read!). Masked rows (~20%): full PSO update, overwrite
//         out_p/out_v. All loads normal; all output stores nontemporal.

typedef float v4f __attribute__((ext_vector_type(4)));

constexpr int DIM     = 512;
constexpr int NPART   = 256 * 256;
constexpr int THREADS = 256;
constexpr int WPB     = THREADS / 64;        // 4 waves per block
constexpr int DIST_BLOCKS = 2048;            // 8192 waves -> 8 rows/wave
constexpr int DIST_WAVES  = DIST_BLOCKS * WPB;
constexpr int DIST_RPW    = NPART / DIST_WAVES;   // 8

__global__ __launch_bounds__(THREADS)
void som_dist(const float* __restrict__ input,
              const float* __restrict__ particles,
              float* __restrict__ out_p,
              unsigned long long* __restrict__ partials) {
    const int lane = threadIdx.x & 63;
    const int wave = threadIdx.x >> 6;
    const int gwave = blockIdx.x * WPB + wave;

    const v4f* in4 = (const v4f*)input;
    const v4f i0 = in4[lane];          // floats [lane*4 .. lane*4+3]
    const v4f i1 = in4[64 + lane];     // floats [256 + lane*4 ..]

    unsigned long long best = ~0ull;
    #pragma unroll
    for (int i = 0; i < DIST_RPW; i += 2) {
        const int rowA = gwave + i * DIST_WAVES;
        const int rowB = rowA + DIST_WAVES;
        const v4f* pa = (const v4f*)(particles + (size_t)rowA * DIM);
        const v4f* pb = (const v4f*)(particles + (size_t)rowB * DIM);
        v4f* oa = (v4f*)(out_p + (size_t)rowA * DIM);
        v4f* ob = (v4f*)(out_p + (size_t)rowB * DIM);
        v4f a0 = pa[lane], a1 = pa[64 + lane];
        v4f b0 = pb[lane], b1 = pb[64 + lane];

        // speculative copy: out_p = particles (masked rows overwritten later)
        __builtin_nontemporal_store(a0, oa + lane);
        __builtin_nontemporal_store(a1, oa + 64 + lane);
        __builtin_nontemporal_store(b0, ob + lane);
        __builtin_nontemporal_store(b1, ob + 64 + lane);

        v4f t, accA, accB;
        t = i0 - a0; accA  = t * t;
        t = i1 - a1; accA += t * t;
        t = i0 - b0; accB  = t * t;
        t = i1 - b1; accB += t * t;
        float dA = accA.x + accA.y + accA.z + accA.w;
        float dB = accB.x + accB.y + accB.z + accB.w;
        #pragma unroll
        for (int off = 32; off >= 1; off >>= 1) {
            dA += __shfl_xor(dA, off, 64);
            dB += __shfl_xor(dB, off, 64);
        }
        unsigned long long encA =
            ((unsigned long long)__float_as_uint(dA) << 32) | (unsigned int)rowA;
        unsigned long long encB =
            ((unsigned long long)__float_as_uint(dB) << 32) | (unsigned int)rowB;
        best = (encA < best) ? encA : best;
        best = (encB < best) ? encB : best;
    }

    __shared__ unsigned long long smin[WPB];
    if (lane == 0) smin[wave] = best;
    __syncthreads();
    if (threadIdx.x == 0) {
        unsigned long long b = smin[0];
        #pragma unroll
        for (int i = 1; i < WPB; ++i) b = (smin[i] < b) ? smin[i] : b;
        partials[blockIdx.x] = b;
    }
}

__global__ __launch_bounds__(256)
void som_reduce(const unsigned long long* __restrict__ partials,
                unsigned long long* __restrict__ out) {
    __shared__ unsigned long long s[256];
    unsigned long long b = ~0ull;
    for (int i = threadIdx.x; i < DIST_BLOCKS; i += 256) {
        unsigned long long v = partials[i];
        b = (v < b) ? v : b;
    }
    s[threadIdx.x] = b;
    __syncthreads();
    #pragma unroll
    for (int off = 128; off >= 1; off >>= 1) {
        if (threadIdx.x < off) {
            unsigned long long v = s[threadIdx.x + off];
            if (v < s[threadIdx.x]) s[threadIdx.x] = v;
        }
        __syncthreads();
    }
    if (threadIdx.x == 0) out[0] = s[0];
}

__global__ __launch_bounds__(THREADS)
void som_update(const float* __restrict__ particles,
                const float* __restrict__ velocities,
                const float* __restrict__ r1,
                const float* __restrict__ r2,
                const int*   __restrict__ grid_loc,
                const int*   __restrict__ iter_num,
                const unsigned long long* __restrict__ bmu_enc,
                float* __restrict__ out_p,
                float* __restrict__ out_v) {
    const int lane = threadIdx.x & 63;
    const int wave = threadIdx.x >> 6;
    // descending: rows touched last by som_dist are read first here (L3 LRU)
    const int row  = (NPART - 1) - (blockIdx.x * WPB + wave);

    const int bmu = (int)(unsigned int)(bmu_enc[0] & 0xffffffffull);
    const float decay   = 1.0f - (float)iter_num[0] * (1.0f / 100.0f);
    const float radius  = 0.3f * decay;
    const float sigma_d = 128.0f * decay;

    const int2 gl = ((const int2*)grid_loc)[row];
    const int2 bl = ((const int2*)grid_loc)[bmu];
    const float dx = (float)gl.x - (float)bl.x;
    const float dy = (float)gl.y - (float)bl.y;
    const float d2 = dx * dx + dy * dy;
    const float nb = expf(-d2 / (sigma_d * sigma_d));
    const bool upd = (1.0f - nb) <= radius;   // global_nbest == exp(0) == 1 exactly

    const size_t base = (size_t)row * DIM;
    const v4f* vv4 = (const v4f*)(velocities + base);
    v4f* ov4 = (v4f*)(out_v + base);

    if (!upd) {
        // wave-uniform branch: out_v = v only; out_p already written by pass 1
        v4f c0 = vv4[lane], c1 = vv4[64 + lane];
        __builtin_nontemporal_store(c0, ov4 + lane);
        __builtin_nontemporal_store(c1, ov4 + 64 + lane);
    } else {
        const v4f* p4 = (const v4f*)(particles + base);
        const v4f* g4 = (const v4f*)(particles + (size_t)bmu * DIM);
        const v4f* x4 = (const v4f*)(r1 + base);
        const v4f* y4 = (const v4f*)(r2 + base);
        v4f* op4 = (v4f*)(out_p + base);
        #pragma unroll
        for (int h = 0; h < 2; ++h) {
            const int idx = h * 64 + lane;
            v4f p = p4[idx];
            v4f v = vv4[idx];
            v4f a = x4[idx];
            v4f c = y4[idx];
            v4f df = g4[idx] - p;
            v4f vn = 0.5f * v + 0.1f * a * df + 0.1f * c * df;
            v4f po = p + vn;
            __builtin_nontemporal_store(vn, ov4 + idx);
            __builtin_nontemporal_store(po, op4 + idx);
        }
    }
}

extern "C" void kernel_launch(void* const* d_in, const int* in_sizes, int n_in,
                              void* d_out, int out_size, void* d_ws, size_t ws_size,
                              hipStream_t stream) {
    const float* input      = (const float*)d_in[0];
    const float* particles  = (const float*)d_in[1];
    const float* velocities = (const float*)d_in[2];
    const float* r1         = (const float*)d_in[3];
    const float* r2         = (const float*)d_in[4];
    const int*   grid_loc   = (const int*)d_in[5];
    const int*   iter_num   = (const int*)d_in[6];

    float* out_p = (float*)d_out;
    float* out_v = out_p + (size_t)NPART * DIM;

    unsigned long long* w         = (unsigned long long*)d_ws;
    unsigned long long* final_enc = w;       // w[0]
    unsigned long long* partials  = w + 8;   // one slot per dist block

    som_dist<<<DIST_BLOCKS, THREADS, 0, stream>>>(input, particles, out_p, partials);
    som_reduce<<<1, 256, 0, stream>>>(partials, final_enc);
    som_update<<<NPART / WPB, THREADS, 0, stream>>>(
        particles, velocities, r1, r2, grid_loc, iter_num, final_enc,
        out_p, out_v);
}

// Round 7
// 111.590 us; speedup vs baseline: 1.0991x; 1.0534x over previous
//
#include <hip/hip_runtime.h>

// SOM/PSO hybrid update, MI355X — 3-kernel pipeline (R3 structure).
// Pass 1: argmin of squared distance (pure-read stream, no stores).
// Pass 2: 1-block min-reduce of 2048 partials -> encoded (distbits<<32)|idx.
// Pass 3: masked PSO update, DESCENDING row order.
//   - particles loads NORMAL (allocate in L3; 134 MB < 256 MB L3 -> the
//     pass-3 re-read should be L3-hit since nothing else allocates)
//   - velocities/r1/r2 loads NONTEMPORAL (streamed once, no-allocate;
//     proven neutral-at-worst by R4-vs-R5 isolation)
//   - output stores NONTEMPORAL (proven good in R3)
// No memset/fill node (R4/R5: graph fill node costs ~11 us).

typedef float v4f __attribute__((ext_vector_type(4)));

constexpr int DIM     = 512;
constexpr int NPART   = 256 * 256;
constexpr int THREADS = 256;
constexpr int WPB     = THREADS / 64;        // 4 waves per block
constexpr int DIST_BLOCKS = 2048;            // 8192 waves -> 8 rows/wave
constexpr int DIST_WAVES  = DIST_BLOCKS * WPB;
constexpr int DIST_RPW    = NPART / DIST_WAVES;   // 8

__global__ __launch_bounds__(THREADS)
void som_dist(const float* __restrict__ input,
              const float* __restrict__ particles,
              unsigned long long* __restrict__ partials) {
    const int lane = threadIdx.x & 63;
    const int wave = threadIdx.x >> 6;
    const int gwave = blockIdx.x * WPB + wave;

    const v4f* in4 = (const v4f*)input;
    const v4f i0 = in4[lane];          // floats [lane*4 .. lane*4+3]
    const v4f i1 = in4[64 + lane];     // floats [256 + lane*4 ..]

    unsigned long long best = ~0ull;
    #pragma unroll
    for (int i = 0; i < DIST_RPW; i += 2) {
        const int rowA = gwave + i * DIST_WAVES;
        const int rowB = rowA + DIST_WAVES;
        const v4f* pa = (const v4f*)(particles + (size_t)rowA * DIM);
        const v4f* pb = (const v4f*)(particles + (size_t)rowB * DIM);
        v4f a0 = pa[lane], a1 = pa[64 + lane];
        v4f b0 = pb[lane], b1 = pb[64 + lane];

        v4f t, accA, accB;
        t = i0 - a0; accA  = t * t;
        t = i1 - a1; accA += t * t;
        t = i0 - b0; accB  = t * t;
        t = i1 - b1; accB += t * t;
        float dA = accA.x + accA.y + accA.z + accA.w;
        float dB = accB.x + accB.y + accB.z + accB.w;
        #pragma unroll
        for (int off = 32; off >= 1; off >>= 1) {
            dA += __shfl_xor(dA, off, 64);
            dB += __shfl_xor(dB, off, 64);
        }
        unsigned long long encA =
            ((unsigned long long)__float_as_uint(dA) << 32) | (unsigned int)rowA;
        unsigned long long encB =
            ((unsigned long long)__float_as_uint(dB) << 32) | (unsigned int)rowB;
        best = (encA < best) ? encA : best;
        best = (encB < best) ? encB : best;
    }

    __shared__ unsigned long long smin[WPB];
    if (lane == 0) smin[wave] = best;
    __syncthreads();
    if (threadIdx.x == 0) {
        unsigned long long b = smin[0];
        #pragma unroll
        for (int i = 1; i < WPB; ++i) b = (smin[i] < b) ? smin[i] : b;
        partials[blockIdx.x] = b;
    }
}

__global__ __launch_bounds__(256)
void som_reduce(const unsigned long long* __restrict__ partials,
                unsigned long long* __restrict__ out) {
    __shared__ unsigned long long s[256];
    unsigned long long b = ~0ull;
    for (int i = threadIdx.x; i < DIST_BLOCKS; i += 256) {
        unsigned long long v = partials[i];
        b = (v < b) ? v : b;
    }
    s[threadIdx.x] = b;
    __syncthreads();
    #pragma unroll
    for (int off = 128; off >= 1; off >>= 1) {
        if (threadIdx.x < off) {
            unsigned long long v = s[threadIdx.x + off];
            if (v < s[threadIdx.x]) s[threadIdx.x] = v;
        }
        __syncthreads();
    }
    if (threadIdx.x == 0) out[0] = s[0];
}

__global__ __launch_bounds__(THREADS)
void som_update(const float* __restrict__ particles,
                const float* __restrict__ velocities,
                const float* __restrict__ r1,
                const float* __restrict__ r2,
                const int*   __restrict__ grid_loc,
                const int*   __restrict__ iter_num,
                const unsigned long long* __restrict__ bmu_enc,
                float* __restrict__ out_p,
                float* __restrict__ out_v) {
    const int lane = threadIdx.x & 63;
    const int wave = threadIdx.x >> 6;
    // descending: rows touched last by som_dist are read first here (L3 LRU)
    const int row  = (NPART - 1) - (blockIdx.x * WPB + wave);

    const int bmu = (int)(unsigned int)(bmu_enc[0] & 0xffffffffull);
    const float decay   = 1.0f - (float)iter_num[0] * (1.0f / 100.0f);
    const float radius  = 0.3f * decay;
    const float sigma_d = 128.0f * decay;

    const int2 gl = ((const int2*)grid_loc)[row];
    const int2 bl = ((const int2*)grid_loc)[bmu];
    const float dx = (float)gl.x - (float)bl.x;
    const float dy = (float)gl.y - (float)bl.y;
    const float d2 = dx * dx + dy * dy;
    const float nb = expf(-d2 / (sigma_d * sigma_d));
    const bool upd = (1.0f - nb) <= radius;   // global_nbest == exp(0) == 1 exactly

    const size_t base = (size_t)row * DIM;
    const v4f* p4  = (const v4f*)(particles  + base);
    const v4f* vv4 = (const v4f*)(velocities + base);
    v4f* op4 = (v4f*)(out_p + base);
    v4f* ov4 = (v4f*)(out_v + base);

    if (!upd) {
        // wave-uniform branch: plain copy, skip r1/r2 reads
        v4f a0 = p4[lane], a1 = p4[64 + lane];                    // L3-hit
        v4f c0 = __builtin_nontemporal_load(vv4 + lane);
        v4f c1 = __builtin_nontemporal_load(vv4 + 64 + lane);
        __builtin_nontemporal_store(a0, op4 + lane);
        __builtin_nontemporal_store(a1, op4 + 64 + lane);
        __builtin_nontemporal_store(c0, ov4 + lane);
        __builtin_nontemporal_store(c1, ov4 + 64 + lane);
    } else {
        const v4f* g4 = (const v4f*)(particles + (size_t)bmu * DIM);
        const v4f* x4 = (const v4f*)(r1 + base);
        const v4f* y4 = (const v4f*)(r2 + base);
        #pragma unroll
        for (int h = 0; h < 2; ++h) {
            const int idx = h * 64 + lane;
            v4f p = p4[idx];                                      // L3-hit
            v4f v = __builtin_nontemporal_load(vv4 + idx);
            v4f a = __builtin_nontemporal_load(x4 + idx);
            v4f c = __builtin_nontemporal_load(y4 + idx);
            v4f df = g4[idx] - p;
            v4f vn = 0.5f * v + 0.1f * a * df + 0.1f * c * df;
            v4f po = p + vn;
            __builtin_nontemporal_store(vn, ov4 + idx);
            __builtin_nontemporal_store(po, op4 + idx);
        }
    }
}

extern "C" void kernel_launch(void* const* d_in, const int* in_sizes, int n_in,
                              void* d_out, int out_size, void* d_ws, size_t ws_size,
                              hipStream_t stream) {
    const float* input      = (const float*)d_in[0];
    const float* particles  = (const float*)d_in[1];
    const float* velocities = (const float*)d_in[2];
    const float* r1         = (const float*)d_in[3];
    const float* r2         = (const float*)d_in[4];
    const int*   grid_loc   = (const int*)d_in[5];
    const int*   iter_num   = (const int*)d_in[6];

    float* out_p = (float*)d_out;
    float* out_v = out_p + (size_t)NPART * DIM;

    unsigned long long* w         = (unsigned long long*)d_ws;
    unsigned long long* final_enc = w;       // w[0]
    unsigned long long* partials  = w + 8;   // one slot per dist block

    som_dist<<<DIST_BLOCKS, THREADS, 0, stream>>>(input, particles, partials);
    som_reduce<<<1, 256, 0, stream>>>(partials, final_enc);
    som_update<<<NPART / WPB, THREADS, 0, stream>>>(
        particles, velocities, r1, r2, grid_loc, iter_num, final_enc,
        out_p, out_v);
}